// Round 4
// baseline (1440.792 us; speedup 1.0000x reference)
//
#include <hip/hip_runtime.h>

// SCAESuite: TopK SAE (up) + pruned-connection downstream SAE.
// n=1024 tokens, D=768, F=8192, K=64, C=128.
// R4: inputs f32 (proven: R2==R3 bit-identical => detector chose f32 path),
//     OUTPUT f32 (reference returns float32; threshold = 2% * max|ref|;
//     R2/R3's absmax 7.95 matches "bf16-packed buffer read as f32" signature).
//   - f64-accumulate GEMMs (exact vs f64 numpy ref at topk boundaries)
//   - exact radix-select top-64 per row (ties -> lowest index)
//   - deduped inverse connection index + per-token LDS scatter
//   - WddT aliases X buffer; ws total ~63.2 MiB

#define NTOK 1024
#define DIM  768
#define FF   8192
#define KK   64
#define CC   128

typedef unsigned short u16;
typedef unsigned int   u32;

__device__ __forceinline__ float bits2f(u32 v) {
    float f;
    __builtin_memcpy(&f, &v, 4);
    return f;
}
__device__ __forceinline__ u32 f2key(float x) {
    u32 u;
    __builtin_memcpy(&u, &x, 4);
    return (u & 0x80000000u) ? ~u : (u | 0x80000000u);
}
__device__ __forceinline__ float key2f(u32 k) {
    u32 u = (k & 0x80000000u) ? (k & 0x7FFFFFFFu) : ~k;
    return bits2f(u);
}

// ---------------- transpose: in f32 [DIM][FF] -> out f32 [FF][DIM] --------------
__global__ __launch_bounds__(256) void transpose_kernel(const float* __restrict__ in,
                                                        float* __restrict__ out) {
    __shared__ float tile[32][33];
    int f0 = blockIdx.x * 32, d0 = blockIdx.y * 32;
    int tx = threadIdx.x, ty = threadIdx.y;   // block (32,8)
#pragma unroll
    for (int i = 0; i < 4; ++i)
        tile[ty + 8 * i][tx] = in[(size_t)(d0 + ty + 8 * i) * FF + f0 + tx];
    __syncthreads();
#pragma unroll
    for (int i = 0; i < 4; ++i)
        out[(size_t)(f0 + ty + 8 * i) * DIM + d0 + tx] = tile[tx][ty + 8 * i];
}

// ---------------- bias dots: s_up = Weu@bdu, t_up = Wed@bdu, t_dn = Wed@bdd -----
__global__ __launch_bounds__(64) void bias_kernel(const float* __restrict__ Weu,
                                                  const float* __restrict__ Wed,
                                                  const float* __restrict__ bdu,
                                                  const float* __restrict__ bdd,
                                                  float* __restrict__ s_up,
                                                  float* __restrict__ t_up,
                                                  float* __restrict__ t_dn) {
    int f = blockIdx.x, lane = threadIdx.x;
    double su = 0.0, tu = 0.0, td = 0.0;
    for (int i = lane; i < DIM; i += 64) {
        float bu = bdu[i], bd = bdd[i];
        su += (double)Weu[(size_t)f * DIM + i] * (double)bu;
        float w = Wed[(size_t)f * DIM + i];
        tu += (double)w * (double)bu;
        td += (double)w * (double)bd;
    }
#pragma unroll
    for (int off = 32; off; off >>= 1) {
        su += __shfl_xor(su, off);
        tu += __shfl_xor(tu, off);
        td += __shfl_xor(td, off);
    }
    if (lane == 0) { s_up[f] = (float)su; t_up[f] = (float)tu; t_dn[f] = (float)td; }
}

// ---------------- GEMM: C[t,f] = sum_d A[t,d]*B[f,d], f64 accumulate ------------
// MODE 0: relu(C - s_up[f] + b_enc[f]) (post_up)   MODE 1: raw (approx0)
template <int MODE>
__global__ __launch_bounds__(256) void gemm_kernel(const float* __restrict__ A,
                                                   const float* __restrict__ B,
                                                   float* __restrict__ Cout,
                                                   const float* __restrict__ s_up,
                                                   const float* __restrict__ b_enc) {
    __shared__ float As[16][68];
    __shared__ float Bs[16][68];
    int tid = threadIdx.x;
    int kk = tid & 15, rr = tid >> 4;       // load coords
    int tx = tid & 15, ty = tid >> 4;       // compute coords
    int m0 = blockIdx.y * 64, n0 = blockIdx.x * 64;
    double acc[4][4] = {};
    for (int k0 = 0; k0 < DIM; k0 += 16) {
#pragma unroll
        for (int i = 0; i < 4; ++i) {
            As[kk][rr + 16 * i] = A[(size_t)(m0 + rr + 16 * i) * DIM + k0 + kk];
            Bs[kk][rr + 16 * i] = B[(size_t)(n0 + rr + 16 * i) * DIM + k0 + kk];
        }
        __syncthreads();
#pragma unroll
        for (int k = 0; k < 16; ++k) {
            float a[4], b[4];
#pragma unroll
            for (int i = 0; i < 4; ++i) { a[i] = As[k][ty * 4 + i]; b[i] = Bs[k][tx * 4 + i]; }
#pragma unroll
            for (int i = 0; i < 4; ++i)
#pragma unroll
                for (int j = 0; j < 4; ++j)
                    acc[i][j] += (double)a[i] * (double)b[j];
        }
        __syncthreads();
    }
#pragma unroll
    for (int i = 0; i < 4; ++i) {
        int t = m0 + ty * 4 + i;
#pragma unroll
        for (int j = 0; j < 4; ++j) {
            int f = n0 + tx * 4 + j;
            float v = (float)acc[i][j];
            if (MODE == 0) {
                v = v - s_up[f] + b_enc[f];
                v = v > 0.f ? v : 0.f;
            }
            Cout[(size_t)t * FF + f] = v;
        }
    }
}

// ---------------- exact top-64 per row via 4x8-bit radix select -----------------
__global__ __launch_bounds__(256) void topk_kernel(const float* __restrict__ Xall,
                                                   float* __restrict__ vals,
                                                   int* __restrict__ idxs) {
    __shared__ u32 hist[256];
    __shared__ u32 sh_prefix;
    __shared__ int sh_k;
    __shared__ u32 sh_cntG, sh_cntE;
    __shared__ int eqidx[256];
    const int r = blockIdx.x, tid = threadIdx.x;
    const float* xr = Xall + (size_t)r * FF;
    if (tid == 0) { sh_prefix = 0; sh_k = KK; }
    __syncthreads();
    for (int pass = 0; pass < 4; ++pass) {
        hist[tid] = 0;
        __syncthreads();
        u32 prefix = sh_prefix;
        int shift = 24 - 8 * pass;
        for (int i = tid; i < FF; i += 256) {
            u32 key = f2key(xr[i]);
            if (pass == 0 || (key >> (shift + 8)) == prefix)
                atomicAdd(&hist[(key >> shift) & 255u], 1u);
        }
        __syncthreads();
        if (tid == 0) {
            int rem = sh_k;
            int b = 255;
            for (; b > 0; --b) {
                int h = (int)hist[b];
                if (rem <= h) break;
                rem -= h;
            }
            sh_prefix = (prefix << 8) | (u32)b;
            sh_k = rem;
        }
        __syncthreads();
    }
    u32 T = sh_prefix;
    int En = sh_k;   // how many ==T survive (lowest indices win)
    if (tid == 0) { sh_cntG = 0; sh_cntE = 0; }
    __syncthreads();
    float* vr = vals + (size_t)r * KK;
    int* ir = idxs + (size_t)r * KK;
    for (int i = tid; i < FF; i += 256) {
        float x = xr[i];
        u32 key = f2key(x);
        if (key > T) {
            u32 p = atomicAdd(&sh_cntG, 1u);
            vr[p] = x; ir[p] = i;
        } else if (key == T) {
            u32 p = atomicAdd(&sh_cntE, 1u);
            if (p < 256) eqidx[p] = i;
        }
    }
    __syncthreads();
    if (tid == 0) {
        int G = (int)sh_cntG;           // == KK - En by construction
        int ne = (int)sh_cntE; if (ne > 256) ne = 256;
        for (int a = 1; a < ne; ++a) {  // ascending index sort (ties: lowest index kept)
            int v = eqidx[a]; int b = a - 1;
            while (b >= 0 && eqidx[b] > v) { eqidx[b + 1] = eqidx[b]; --b; }
            eqidx[b + 1] = v;
        }
        float tv = key2f(T);
        for (int q = 0; q < En && q < ne; ++q) { vr[G + q] = tv; ir[G + q] = eqidx[q]; }
    }
}

// ---------------- conn dedupe + inverse-index build -----------------------------
__global__ __launch_bounds__(128) void dedup_deg_kernel(const int* __restrict__ conn,
                                                        u32* __restrict__ deg) {
    __shared__ int row[CC];
    int fd = blockIdx.x, c = threadIdx.x;
    int v = conn[(size_t)fd * CC + c];
    row[c] = v;
    __syncthreads();
    bool dup = false;
    for (int j = 0; j < c; ++j) dup |= (row[j] == v);
    if (!dup) atomicAdd(&deg[v], 1u);
}

__global__ __launch_bounds__(256) void scan_kernel(const u32* __restrict__ deg,
                                                   u32* __restrict__ offs) {
    __shared__ u32 sdeg[FF];
    __shared__ u32 part[256];
    int tid = threadIdx.x;
    for (int i = tid; i < FF; i += 256) sdeg[i] = deg[i];
    __syncthreads();
    u32 s = 0;
    for (int j = 0; j < 32; ++j) s += sdeg[tid * 32 + j];
    part[tid] = s;
    __syncthreads();
    if (tid == 0) {
        u32 run = 0;
        for (int i = 0; i < 256; ++i) { u32 v = part[i]; part[i] = run; run += v; }
        offs[FF] = run;
    }
    __syncthreads();
    u32 run = part[tid];
    for (int j = 0; j < 32; ++j) { offs[tid * 32 + j] = run; run += sdeg[tid * 32 + j]; }
}

__global__ __launch_bounds__(128) void fill_kernel(const int* __restrict__ conn,
                                                   const u32* __restrict__ offs,
                                                   u32* __restrict__ cursor,
                                                   u16* __restrict__ inv_fd) {
    __shared__ int row[CC];
    int fd = blockIdx.x, c = threadIdx.x;
    int v = conn[(size_t)fd * CC + c];
    row[c] = v;
    __syncthreads();
    bool dup = false;
    for (int j = 0; j < c; ++j) dup |= (row[j] == v);
    if (!dup) {
        u32 slot = atomicAdd(&cursor[v], 1u);
        inv_fd[offs[v] + slot] = (u16)fd;
    }
}

// ---------------- virtual values per inverse-index entry ------------------------
// v_inv[p] = dot(W_enc_down[fd,:], W_dec_up[:,fu]) for p in [offs[fu],offs[fu+1])
__global__ __launch_bounds__(256) void vconn_kernel(const float* __restrict__ Wed,
                                                    const float* __restrict__ WduT,
                                                    const u32* __restrict__ offs,
                                                    const u16* __restrict__ inv_fd,
                                                    float* __restrict__ v_inv) {
    __shared__ float row[DIM];
    int fu = blockIdx.x;
    for (int i = threadIdx.x; i < DIM; i += 256) row[i] = WduT[(size_t)fu * DIM + i];
    __syncthreads();
    u32 s = offs[fu], e = offs[fu + 1];
    int wave = threadIdx.x >> 6, lane = threadIdx.x & 63;
    const float4* row4 = (const float4*)row;
    for (u32 p = s + wave; p < e; p += 4) {
        int fd = (int)inv_fd[p];
        const float4* wr = (const float4*)(Wed + (size_t)fd * DIM);
        float acc = 0.f;
#pragma unroll
        for (int i = 0; i < 3; ++i) {
            float4 u = wr[lane + 64 * i];
            float4 rv = row4[lane + 64 * i];
            acc = fmaf(u.x, rv.x, acc);
            acc = fmaf(u.y, rv.y, acc);
            acc = fmaf(u.z, rv.z, acc);
            acc = fmaf(u.w, rv.w, acc);
        }
#pragma unroll
        for (int off = 32; off; off >>= 1) acc += __shfl_xor(acc, off);
        if (lane == 0) v_inv[p] = acc;
    }
}

// ---------------- per-token pruned scatter + epilogue ---------------------------
__global__ __launch_bounds__(256) void phase2_kernel(float* __restrict__ X,
                                                     const float* __restrict__ vals_up,
                                                     const int* __restrict__ idx_up,
                                                     const u32* __restrict__ offs,
                                                     const u16* __restrict__ inv_fd,
                                                     const float* __restrict__ v_inv,
                                                     const float* __restrict__ t_up,
                                                     const float* __restrict__ t_dn,
                                                     const float* __restrict__ b_enc_down,
                                                     const float* __restrict__ ln) {
    __shared__ float acc[FF];
    __shared__ float z[KK];
    __shared__ int fidx[KK];
    int t = blockIdx.x, tid = threadIdx.x;
    for (int i = tid; i < FF; i += 256) acc[i] = 0.f;
    if (tid < KK) { z[tid] = vals_up[(size_t)t * KK + tid]; fidx[tid] = idx_up[(size_t)t * KK + tid]; }
    __syncthreads();
    for (int j = 0; j < KK; ++j) {
        float zj = z[j];
        int f = fidx[j];
        u32 s = offs[f], e = offs[f + 1];
        for (u32 p = s + tid; p < e; p += 256)
            atomicAdd(&acc[(int)inv_fd[p]], zj * v_inv[p]);
    }
    __syncthreads();
    float lnv = ln[t];
    for (int i = tid; i < FF; i += 256) {
        float v = X[(size_t)t * FF + i] + acc[i] + t_up[i];
        v = v / lnv + b_enc_down[i] - t_dn[i];
        X[(size_t)t * FF + i] = v;
    }
}

// ---------------- sparse decode: out[t,d] = sum_j z_j * WdT[f_j,d] + b[d] -------
__global__ __launch_bounds__(256) void decode_kernel(const float* __restrict__ vals,
                                                     const int* __restrict__ idxs,
                                                     const float* __restrict__ WdT,
                                                     const float* __restrict__ b_dec,
                                                     float* __restrict__ outp) {
    __shared__ float z[KK];
    __shared__ int fidx[KK];
    int t = blockIdx.x, tid = threadIdx.x;
    if (tid < KK) { z[tid] = vals[(size_t)t * KK + tid]; fidx[tid] = idxs[(size_t)t * KK + tid]; }
    __syncthreads();
    float a0 = 0.f, a1 = 0.f, a2 = 0.f;
    for (int j = 0; j < KK; ++j) {
        const float* wr = WdT + (size_t)fidx[j] * DIM;
        float zj = z[j];
        a0 = fmaf(zj, wr[tid], a0);
        a1 = fmaf(zj, wr[tid + 256], a1);
        a2 = fmaf(zj, wr[tid + 512], a2);
    }
    outp[(size_t)t * DIM + tid]       = a0 + b_dec[tid];
    outp[(size_t)t * DIM + tid + 256] = a1 + b_dec[tid + 256];
    outp[(size_t)t * DIM + tid + 512] = a2 + b_dec[tid + 512];
}

extern "C" void kernel_launch(void* const* d_in, const int* in_sizes, int n_in,
                              void* d_out, int out_size, void* d_ws, size_t ws_size,
                              hipStream_t stream) {
    const float* x0  = (const float*)d_in[0];   // initial_acts [n,D]
    const float* xu  = (const float*)d_in[1];   // x_up [n,D]
    const float* ln  = (const float*)d_in[2];   // ln_scale [n]
    const float* Weu = (const float*)d_in[3];   // W_enc_up [F,D]
    const float* beu = (const float*)d_in[4];   // b_enc_up [F]
    const float* Wdu = (const float*)d_in[5];   // W_dec_up [D,F]
    const float* bdu = (const float*)d_in[6];   // b_dec_up [D]
    const float* Wed = (const float*)d_in[7];   // W_enc_down [F,D]
    const float* bed = (const float*)d_in[8];   // b_enc_down [F]
    const float* Wdd = (const float*)d_in[9];   // W_dec_down [D,F]
    const float* bdd = (const float*)d_in[10];  // b_dec_down [D]
    const int* conn = (const int*)d_in[11];     // [F,C]
    float* out = (float*)d_out;                 // f32! [2, n, D] flat

    // workspace carve-up — ~63.2 MiB total
    char* w = (char*)d_ws;
    float* X       = (float*)w;                       // [NTOK*FF] f32 (32 MiB)
    float* WddT    = X;                               // ALIAS: used only after topk_dn
    float* WduT    = X + (size_t)NTOK * FF;           // [FF*DIM] f32 (24 MiB)
    float* vals_up = WduT + (size_t)FF * DIM;         // [NTOK*KK]
    int*   idx_up  = (int*)(vals_up + NTOK * KK);
    float* vals_dn = (float*)(idx_up + NTOK * KK);
    int*   idx_dn  = (int*)(vals_dn + NTOK * KK);
    float* s_up    = (float*)(idx_dn + NTOK * KK);    // [FF]
    float* t_up    = s_up + FF;
    float* t_dn    = t_up + FF;
    u32*   deg     = (u32*)(t_dn + FF);               // [FF]
    u32*   cursor  = deg + FF;                        // [FF]
    u32*   offs    = cursor + FF;                     // [FF+1] (+pad)
    u16*   inv_fd  = (u16*)(offs + FF + 8);           // [FF*CC] u16 (2 MiB)
    float* v_inv   = (float*)(inv_fd + (size_t)FF * CC); // 4 MiB

    dim3 tgrid(FF / 32, DIM / 32), tblk(32, 8);
    dim3 ggrid(FF / 64, NTOK / 64);

    // W_dec_up transpose to [F][D] + bias dot vectors
    transpose_kernel<<<tgrid, tblk, 0, stream>>>(Wdu, WduT);
    bias_kernel<<<FF, 64, 0, stream>>>(Weu, Wed, bdu, bdd, s_up, t_up, t_dn);

    // inverse connection index
    hipMemsetAsync(deg, 0, 2 * FF * sizeof(u32), stream);  // deg + cursor
    dedup_deg_kernel<<<FF, CC, 0, stream>>>(conn, deg);
    scan_kernel<<<1, 256, 0, stream>>>(deg, offs);
    fill_kernel<<<FF, CC, 0, stream>>>(conn, offs, cursor, inv_fd);
    vconn_kernel<<<FF, 256, 0, stream>>>(Wed, WduT, offs, inv_fd, v_inv);

    // upstream SAE encode + topk
    gemm_kernel<0><<<ggrid, 256, 0, stream>>>(xu, Weu, X, s_up, beu);
    topk_kernel<<<NTOK, 256, 0, stream>>>(X, vals_up, idx_up);

    // downstream approx + topk
    gemm_kernel<1><<<ggrid, 256, 0, stream>>>(x0, Wed, X, s_up, beu);
    phase2_kernel<<<NTOK, 256, 0, stream>>>(X, vals_up, idx_up, offs, inv_fd, v_inv,
                                            t_up, t_dn, bed, ln);
    topk_kernel<<<NTOK, 256, 0, stream>>>(X, vals_dn, idx_dn);

    // decode up (before X is clobbered by WddT)
    decode_kernel<<<NTOK, 256, 0, stream>>>(vals_up, idx_up, WduT, bdu, out);

    // transpose W_dec_down into the (now free) X buffer, then decode down
    transpose_kernel<<<tgrid, tblk, 0, stream>>>(Wdd, WddT);
    decode_kernel<<<NTOK, 256, 0, stream>>>(vals_dn, idx_dn, WddT, bdd,
                                            out + (size_t)NTOK * DIM);
}

// Round 5
// 863.832 us; speedup vs baseline: 1.6679x; 1.6679x over previous
//
#include <hip/hip_runtime.h>

// SCAESuite R5: approx bf16-MFMA selection + exact f64 candidate rescoring.
// n=1024 tokens, D=768, F=8192, K=64, C=128. Inputs f32, output f32.
//  - gemm_mfma: bf16 16x16x32 MFMA, 128x128 tile -> X bf16 (selection only)
//  - select: 4-pass radix for approx rank-96 threshold, collect <=128 cand idx
//  - fixup: exact f64 rescore of candidates (incl. pruned virtual terms via
//    conn bitmap), bitonic top-64 (ties -> lowest index) == R4-proven values
//  - vconn gathers bf16 Wed (halved traffic), v_inv stored bf16
//  - ws ~62.9 MiB (< R4's proven 63.2); WddT aliases [X16|B16]

#define NTOK 1024
#define DIM  768
#define FF   8192
#define KK   64
#define CC   128
#define KSEL 96
#define CAP  128

typedef unsigned short u16;
typedef unsigned int   u32;
typedef __attribute__((ext_vector_type(8))) short short8;
typedef __attribute__((ext_vector_type(4))) float floatx4;

__device__ __forceinline__ float bits2f(u32 v) {
    float f; __builtin_memcpy(&f, &v, 4); return f;
}
__device__ __forceinline__ float bf2f(u16 u) { return bits2f(((u32)u) << 16); }
__device__ __forceinline__ u16 f2bf(float f) {
    u32 u; __builtin_memcpy(&u, &f, 4);
    u32 lsb = (u >> 16) & 1u;
    u += 0x7fffu + lsb;
    return (u16)(u >> 16);
}
__device__ __forceinline__ u32 f2key(float x) {
    u32 u; __builtin_memcpy(&u, &x, 4);
    return (u & 0x80000000u) ? ~u : (u | 0x80000000u);
}

// ---------------- f32 -> bf16 bulk convert (n multiple of 4) -------------------
__global__ __launch_bounds__(256) void convert_kernel(const float* __restrict__ src,
                                                      u16* __restrict__ dst, int n4) {
    int i = blockIdx.x * 256 + threadIdx.x;
    if (i < n4) {
        float4 v = ((const float4*)src)[i];
        ushort4 o;
        o.x = f2bf(v.x); o.y = f2bf(v.y); o.z = f2bf(v.z); o.w = f2bf(v.w);
        ((ushort4*)dst)[i] = o;
    }
}

// ---------------- transpose: f32 [DIM][FF] -> f32 [FF][DIM] ---------------------
__global__ __launch_bounds__(256) void transpose_kernel(const float* __restrict__ in,
                                                        float* __restrict__ out) {
    __shared__ float tile[32][33];
    int f0 = blockIdx.x * 32, d0 = blockIdx.y * 32;
    int tx = threadIdx.x, ty = threadIdx.y;
#pragma unroll
    for (int i = 0; i < 4; ++i)
        tile[ty + 8 * i][tx] = in[(size_t)(d0 + ty + 8 * i) * FF + f0 + tx];
    __syncthreads();
#pragma unroll
    for (int i = 0; i < 4; ++i)
        out[(size_t)(f0 + ty + 8 * i) * DIM + d0 + tx] = tile[tx][ty + 8 * i];
}

// ---------------- bias dots (f32 + f64 copies) ----------------------------------
__global__ __launch_bounds__(64) void bias_kernel(const float* __restrict__ Weu,
                                                  const float* __restrict__ Wed,
                                                  const float* __restrict__ bdu,
                                                  const float* __restrict__ bdd,
                                                  float* __restrict__ sF,
                                                  float* __restrict__ tuF,
                                                  float* __restrict__ tdF,
                                                  double* __restrict__ s64,
                                                  double* __restrict__ tu64,
                                                  double* __restrict__ td64) {
    int f = blockIdx.x, lane = threadIdx.x;
    double su = 0.0, tu = 0.0, td = 0.0;
    for (int i = lane; i < DIM; i += 64) {
        double bu = (double)bdu[i], bd = (double)bdd[i];
        su += (double)Weu[(size_t)f * DIM + i] * bu;
        double w = (double)Wed[(size_t)f * DIM + i];
        tu += w * bu;
        td += w * bd;
    }
#pragma unroll
    for (int off = 32; off; off >>= 1) {
        su += __shfl_xor(su, off);
        tu += __shfl_xor(tu, off);
        td += __shfl_xor(td, off);
    }
    if (lane == 0) {
        sF[f] = (float)su; tuF[f] = (float)tu; tdF[f] = (float)td;
        s64[f] = su; tu64[f] = tu; td64[f] = td;
    }
}

// ---------------- bf16 MFMA GEMM: X[t,f] = sum_d A[t,d]*B[f,d] ------------------
// MODE 0: relu(X - sF[f] + beu[f])   MODE 1: raw.  Output bf16 (selection only).
template <int MODE>
__global__ __launch_bounds__(256) void gemm_mfma(const u16* __restrict__ A16,
                                                 const u16* __restrict__ B16,
                                                 u16* __restrict__ Xout,
                                                 const float* __restrict__ sF,
                                                 const float* __restrict__ b_enc) {
    // LDS rows padded to 40 u16 (80 B) -> conflict-free b128 frag reads
    __shared__ __align__(16) u16 As[128 * 40];
    __shared__ __align__(16) u16 Bs[128 * 40];
    int tid = threadIdx.x;
    int wave = tid >> 6, lane = tid & 63;
    int lm = lane & 15, quad = lane >> 4;
    int m0 = blockIdx.y * 128, n0 = blockIdx.x * 128;
    int wm = (wave >> 1) * 64, wn = (wave & 1) * 64;
    floatx4 acc[4][4];
#pragma unroll
    for (int i = 0; i < 4; ++i)
#pragma unroll
        for (int j = 0; j < 4; ++j)
            acc[i][j] = (floatx4){0.f, 0.f, 0.f, 0.f};
    int r = tid >> 2;            // staging row 0..63 (and +64)
    int s = (tid & 3) * 8;       // k-elem offset {0,8,16,24}
    const u16* gA = A16 + (size_t)(m0 + r) * DIM + s;
    const u16* gB = B16 + (size_t)(n0 + r) * DIM + s;
    for (int k0 = 0; k0 < DIM; k0 += 32) {
        __syncthreads();
        *(int4*)&As[r * 40 + s]          = *(const int4*)(gA + k0);
        *(int4*)&As[(r + 64) * 40 + s]   = *(const int4*)(gA + (size_t)64 * DIM + k0);
        *(int4*)&Bs[r * 40 + s]          = *(const int4*)(gB + k0);
        *(int4*)&Bs[(r + 64) * 40 + s]   = *(const int4*)(gB + (size_t)64 * DIM + k0);
        __syncthreads();
        short8 af[4], bfr[4];
#pragma unroll
        for (int mi = 0; mi < 4; ++mi)
            af[mi] = *(const short8*)&As[(wm + mi * 16 + lm) * 40 + quad * 8];
#pragma unroll
        for (int ni = 0; ni < 4; ++ni)
            bfr[ni] = *(const short8*)&Bs[(wn + ni * 16 + lm) * 40 + quad * 8];
#pragma unroll
        for (int mi = 0; mi < 4; ++mi)
#pragma unroll
            for (int ni = 0; ni < 4; ++ni)
                acc[mi][ni] = __builtin_amdgcn_mfma_f32_16x16x32_bf16(
                    af[mi], bfr[ni], acc[mi][ni], 0, 0, 0);
    }
#pragma unroll
    for (int ni = 0; ni < 4; ++ni) {
        int col = n0 + wn + ni * 16 + lm;
        float sub = 0.f, bb = 0.f;
        if (MODE == 0) { sub = sF[col]; bb = b_enc[col]; }
#pragma unroll
        for (int mi = 0; mi < 4; ++mi) {
#pragma unroll
            for (int reg = 0; reg < 4; ++reg) {
                int row = m0 + wm + mi * 16 + quad * 4 + reg;
                float v = acc[mi][ni][reg];
                if (MODE == 0) { v = v - sub + bb; v = v > 0.f ? v : 0.f; }
                Xout[(size_t)row * FF + col] = f2bf(v);
            }
        }
    }
}

// ---------------- approx top-KSEL candidate collection (radix) ------------------
__global__ __launch_bounds__(256) void select_kernel(const u16* __restrict__ X16,
                                                     u16* __restrict__ cand,
                                                     int* __restrict__ cnt) {
    __shared__ u32 hist[256];
    __shared__ u32 sh_prefix;
    __shared__ int sh_k;
    __shared__ u32 sh_cntG, sh_cntE;
    __shared__ int eqidx[256];
    const int rrow = blockIdx.x, tid = threadIdx.x;
    const u16* xr = X16 + (size_t)rrow * FF;
    if (tid == 0) { sh_prefix = 0; sh_k = KSEL; }
    __syncthreads();
    for (int pass = 0; pass < 4; ++pass) {
        hist[tid] = 0;
        __syncthreads();
        u32 prefix = sh_prefix;
        int shift = 24 - 8 * pass;
        for (int i = tid; i < FF; i += 256) {
            u32 key = f2key(bf2f(xr[i]));
            if (pass == 0 || (key >> (shift + 8)) == prefix)
                atomicAdd(&hist[(key >> shift) & 255u], 1u);
        }
        __syncthreads();
        if (tid == 0) {
            int rem = sh_k;
            int b = 255;
            for (; b > 0; --b) {
                int h = (int)hist[b];
                if (rem <= h) break;
                rem -= h;
            }
            sh_prefix = (prefix << 8) | (u32)b;
            sh_k = rem;
        }
        __syncthreads();
    }
    u32 T = sh_prefix;
    if (tid == 0) { sh_cntG = 0; sh_cntE = 0; }
    __syncthreads();
    u16* cr = cand + (size_t)rrow * CAP;
    for (int i = tid; i < FF; i += 256) {
        u32 key = f2key(bf2f(xr[i]));
        if (key > T) {
            u32 p = atomicAdd(&sh_cntG, 1u);
            if (p < CAP) cr[p] = (u16)i;
        } else if (key == T) {
            u32 p = atomicAdd(&sh_cntE, 1u);
            if (p < 256) eqidx[p] = i;
        }
    }
    __syncthreads();
    if (tid == 0) {
        int G = (int)sh_cntG; if (G > CAP) G = CAP;   // G <= KSEL-1 by construction
        int ne = (int)sh_cntE; if (ne > 256) ne = 256;
        int total = G;
        for (int q = 0; q < ne && total < CAP; ++q) cr[total++] = (u16)eqidx[q];
        cnt[rrow] = total;
    }
}

// ---------------- bitonic sort of 128 (desc by val, asc idx) --------------------
__device__ __forceinline__ bool sort_before(double av, int ai, double bv, int bi) {
    return (av > bv) || (av == bv && ai < bi);
}
__device__ void bitonic128(double* sv, int* si, int tid) {
    for (int k = 2; k <= 128; k <<= 1) {
        for (int j = k >> 1; j > 0; j >>= 1) {
            __syncthreads();
            if (tid < 64) {
                int i = ((tid & ~(j - 1)) << 1) | (tid & (j - 1));
                int l = i, rr = i + j;
                bool bfirst = sort_before(sv[rr], si[rr], sv[l], si[l]);
                bool doswap = ((i & k) == 0) ? bfirst : !bfirst;
                if (doswap) {
                    double tv = sv[l]; sv[l] = sv[rr]; sv[rr] = tv;
                    int ti = si[l]; si[l] = si[rr]; si[rr] = ti;
                }
            }
        }
    }
    __syncthreads();
}

// ---------------- exact rescore (up): relu(xu.Weu[f] - s64 + beu) ---------------
__global__ __launch_bounds__(256) void fixup_up(const float* __restrict__ xu,
                                                const float* __restrict__ Weu,
                                                const double* __restrict__ s64,
                                                const float* __restrict__ beu,
                                                const u16* __restrict__ cand,
                                                const int* __restrict__ cnt,
                                                float* __restrict__ vals,
                                                int* __restrict__ idxs) {
    __shared__ float xrow[DIM];
    __shared__ double sv[128];
    __shared__ int si[128];
    int t = blockIdx.x, tid = threadIdx.x, wave = tid >> 6, lane = tid & 63;
    for (int i = tid; i < DIM; i += 256) xrow[i] = xu[(size_t)t * DIM + i];
    for (int c = tid; c < 128; c += 256) { sv[c] = -1.0e300; si[c] = 0x7fffffff; }
    __syncthreads();
    int nc = cnt[t]; if (nc > 128) nc = 128;
    for (int c = wave; c < nc; c += 4) {
        int f = (int)cand[(size_t)t * CAP + c];
        const float* wr = Weu + (size_t)f * DIM;
        double p = 0.0;
#pragma unroll
        for (int i = 0; i < 12; ++i) {
            int d = lane + 64 * i;
            p += (double)xrow[d] * (double)wr[d];
        }
#pragma unroll
        for (int off = 32; off; off >>= 1) p += __shfl_xor(p, off);
        if (lane == 0) {
            double v = p - s64[f] + (double)beu[f];
            v = v > 0.0 ? v : 0.0;
            sv[c] = v; si[c] = f;
        }
    }
    __syncthreads();
    bitonic128(sv, si, tid);
    if (tid < KK) {
        vals[(size_t)t * KK + tid] = (float)sv[tid];
        idxs[(size_t)t * KK + tid] = si[tid];
    }
}

// ---------------- exact rescore (down) ------------------------------------------
__global__ __launch_bounds__(256) void fixup_dn(const float* __restrict__ x0,
                                                const float* __restrict__ Wed,
                                                const float* __restrict__ WduT,
                                                const double* __restrict__ tu64,
                                                const double* __restrict__ td64,
                                                const float* __restrict__ bed,
                                                const float* __restrict__ ln,
                                                const u16* __restrict__ cclean,
                                                const float* __restrict__ vals_up,
                                                const int* __restrict__ idx_up,
                                                const u16* __restrict__ cand,
                                                const int* __restrict__ cnt,
                                                float* __restrict__ vals,
                                                int* __restrict__ idxs) {
    __shared__ float xrow[DIM];
    __shared__ u32 bm[256];
    __shared__ int fl[KK];
    __shared__ float zl[KK];
    __shared__ double sv[128];
    __shared__ int si[128];
    int t = blockIdx.x, tid = threadIdx.x, wave = tid >> 6, lane = tid & 63;
    for (int i = tid; i < DIM; i += 256) xrow[i] = x0[(size_t)t * DIM + i];
    if (tid < 256) bm[tid] = 0;
    for (int c = tid; c < 128; c += 256) { sv[c] = -1.0e300; si[c] = 0x7fffffff; }
    __syncthreads();
    if (tid < KK) {
        int f = idx_up[(size_t)t * KK + tid];
        fl[tid] = f; zl[tid] = vals_up[(size_t)t * KK + tid];
        atomicOr(&bm[f >> 5], 1u << (f & 31));
    }
    __syncthreads();
    int nc = cnt[t]; if (nc > 128) nc = 128;
    double lnt = (double)ln[t];
    for (int c = wave; c < nc; c += 4) {
        int f = (int)cand[(size_t)t * CAP + c];
        const float* wr = Wed + (size_t)f * DIM;
        double p = 0.0;
#pragma unroll
        for (int i = 0; i < 12; ++i) {
            int d = lane + 64 * i;
            p += (double)xrow[d] * (double)wr[d];
        }
        const u16* crow = cclean + (size_t)f * CC;
        int e0 = (int)crow[lane], e1 = (int)crow[lane + 64];
        bool h0 = (e0 != 0xFFFF) && ((bm[e0 >> 5] >> (e0 & 31)) & 1u);
        bool h1 = (e1 != 0xFFFF) && ((bm[e1 >> 5] >> (e1 & 31)) & 1u);
        unsigned long long m0 = __ballot(h0), m1 = __ballot(h1);
        while (m0 | m1) {
            int fu;
            if (m0) {
                int b = __ffsll((long long)m0) - 1; m0 &= m0 - 1;
                fu = __shfl(e0, b);
            } else {
                int b = __ffsll((long long)m1) - 1; m1 &= m1 - 1;
                fu = __shfl(e1, b);
            }
            unsigned long long zm = __ballot(fl[lane & 63] == fu && lane < KK);
            float z = zl[__ffsll((long long)zm) - 1];
            const float* du = WduT + (size_t)fu * DIM;
            double vp = 0.0;
#pragma unroll
            for (int i = 0; i < 12; ++i) {
                int d = lane + 64 * i;
                vp += (double)wr[d] * (double)du[d];
            }
            p += (double)z * vp;
        }
#pragma unroll
        for (int off = 32; off; off >>= 1) p += __shfl_xor(p, off);
        if (lane == 0) {
            double v = (p + tu64[f]) / lnt + (double)bed[f] - td64[f];
            sv[c] = v; si[c] = f;
        }
    }
    __syncthreads();
    bitonic128(sv, si, tid);
    if (tid < KK) {
        vals[(size_t)t * KK + tid] = (float)sv[tid];
        idxs[(size_t)t * KK + tid] = si[tid];
    }
}

// ---------------- conn dedupe + inverse-index build -----------------------------
__global__ __launch_bounds__(128) void dedup_deg_kernel(const int* __restrict__ conn,
                                                        u32* __restrict__ deg) {
    __shared__ int row[CC];
    int fd = blockIdx.x, c = threadIdx.x;
    int v = conn[(size_t)fd * CC + c];
    row[c] = v;
    __syncthreads();
    bool dup = false;
    for (int j = 0; j < c; ++j) dup |= (row[j] == v);
    if (!dup) atomicAdd(&deg[v], 1u);
}

__global__ __launch_bounds__(256) void scan_kernel(const u32* __restrict__ deg,
                                                   u32* __restrict__ offs) {
    __shared__ u32 sdeg[FF];
    __shared__ u32 part[256];
    int tid = threadIdx.x;
    for (int i = tid; i < FF; i += 256) sdeg[i] = deg[i];
    __syncthreads();
    u32 s = 0;
    for (int j = 0; j < 32; ++j) s += sdeg[tid * 32 + j];
    part[tid] = s;
    __syncthreads();
    if (tid == 0) {
        u32 run = 0;
        for (int i = 0; i < 256; ++i) { u32 v = part[i]; part[i] = run; run += v; }
        offs[FF] = run;
    }
    __syncthreads();
    u32 run = part[tid];
    for (int j = 0; j < 32; ++j) { offs[tid * 32 + j] = run; run += sdeg[tid * 32 + j]; }
}

__global__ __launch_bounds__(128) void fill_kernel(const int* __restrict__ conn,
                                                   const u32* __restrict__ offs,
                                                   u32* __restrict__ cursor,
                                                   u16* __restrict__ inv_fd,
                                                   u16* __restrict__ cclean) {
    __shared__ int row[CC];
    int fd = blockIdx.x, c = threadIdx.x;
    int v = conn[(size_t)fd * CC + c];
    row[c] = v;
    __syncthreads();
    bool dup = false;
    for (int j = 0; j < c; ++j) dup |= (row[j] == v);
    cclean[(size_t)fd * CC + c] = dup ? (u16)0xFFFF : (u16)v;
    if (!dup) {
        u32 slot = atomicAdd(&cursor[v], 1u);
        inv_fd[offs[v] + slot] = (u16)fd;
    }
}

// ---------------- virtual values per inverse-index entry (bf16 gather) ----------
__global__ __launch_bounds__(256) void vconn_kernel(const u16* __restrict__ Wed16,
                                                    const float* __restrict__ WduT,
                                                    const u32* __restrict__ offs,
                                                    const u16* __restrict__ inv_fd,
                                                    u16* __restrict__ v_inv16) {
    __shared__ float row[DIM];
    int fu = blockIdx.x;
    for (int i = threadIdx.x; i < DIM; i += 256) row[i] = WduT[(size_t)fu * DIM + i];
    __syncthreads();
    u32 s = offs[fu], e = offs[fu + 1];
    int wave = threadIdx.x >> 6, lane = threadIdx.x & 63;
    const float4* row4 = (const float4*)row;
    for (u32 p = s + wave; p < e; p += 4) {
        int fd = (int)inv_fd[p];
        const ushort4* wr = (const ushort4*)(Wed16 + (size_t)fd * DIM);
        float acc = 0.f;
#pragma unroll
        for (int i = 0; i < 3; ++i) {
            ushort4 u = wr[lane + 64 * i];
            float4 rv = row4[lane + 64 * i];
            acc = fmaf(bf2f(u.x), rv.x, acc);
            acc = fmaf(bf2f(u.y), rv.y, acc);
            acc = fmaf(bf2f(u.z), rv.z, acc);
            acc = fmaf(bf2f(u.w), rv.w, acc);
        }
#pragma unroll
        for (int off = 32; off; off >>= 1) acc += __shfl_xor(acc, off);
        if (lane == 0) v_inv16[p] = f2bf(acc);
    }
}

// ---------------- per-token pruned scatter + epilogue (approx, bf16 X) ----------
__global__ __launch_bounds__(256) void phase2_kernel(u16* __restrict__ X16,
                                                     const float* __restrict__ vals_up,
                                                     const int* __restrict__ idx_up,
                                                     const u32* __restrict__ offs,
                                                     const u16* __restrict__ inv_fd,
                                                     const u16* __restrict__ v_inv16,
                                                     const float* __restrict__ tuF,
                                                     const float* __restrict__ tdF,
                                                     const float* __restrict__ bed,
                                                     const float* __restrict__ ln) {
    __shared__ float acc[FF];
    __shared__ float z[KK];
    __shared__ int fidx[KK];
    int t = blockIdx.x, tid = threadIdx.x;
    for (int i = tid; i < FF; i += 256) acc[i] = 0.f;
    if (tid < KK) { z[tid] = vals_up[(size_t)t * KK + tid]; fidx[tid] = idx_up[(size_t)t * KK + tid]; }
    __syncthreads();
    for (int j = 0; j < KK; ++j) {
        float zj = z[j];
        int f = fidx[j];
        u32 s = offs[f], e = offs[f + 1];
        for (u32 p = s + tid; p < e; p += 256)
            atomicAdd(&acc[(int)inv_fd[p]], zj * bf2f(v_inv16[p]));
    }
    __syncthreads();
    float lnv = ln[t];
    for (int i = tid; i < FF; i += 256) {
        float v = bf2f(X16[(size_t)t * FF + i]) + acc[i] + tuF[i];
        v = v / lnv + bed[i] - tdF[i];
        X16[(size_t)t * FF + i] = f2bf(v);
    }
}

// ---------------- sparse decode: out[t,d] = sum_j z_j * WdT[f_j,d] + b[d] -------
__global__ __launch_bounds__(256) void decode_kernel(const float* __restrict__ vals,
                                                     const int* __restrict__ idxs,
                                                     const float* __restrict__ WdT,
                                                     const float* __restrict__ b_dec,
                                                     float* __restrict__ outp) {
    __shared__ float z[KK];
    __shared__ int fidx[KK];
    int t = blockIdx.x, tid = threadIdx.x;
    if (tid < KK) { z[tid] = vals[(size_t)t * KK + tid]; fidx[tid] = idxs[(size_t)t * KK + tid]; }
    __syncthreads();
    float a0 = 0.f, a1 = 0.f, a2 = 0.f;
    for (int j = 0; j < KK; ++j) {
        const float* wr = WdT + (size_t)fidx[j] * DIM;
        float zj = z[j];
        a0 = fmaf(zj, wr[tid], a0);
        a1 = fmaf(zj, wr[tid + 256], a1);
        a2 = fmaf(zj, wr[tid + 512], a2);
    }
    outp[(size_t)t * DIM + tid]       = a0 + b_dec[tid];
    outp[(size_t)t * DIM + tid + 256] = a1 + b_dec[tid + 256];
    outp[(size_t)t * DIM + tid + 512] = a2 + b_dec[tid + 512];
}

extern "C" void kernel_launch(void* const* d_in, const int* in_sizes, int n_in,
                              void* d_out, int out_size, void* d_ws, size_t ws_size,
                              hipStream_t stream) {
    const float* x0  = (const float*)d_in[0];
    const float* xu  = (const float*)d_in[1];
    const float* ln  = (const float*)d_in[2];
    const float* Weu = (const float*)d_in[3];
    const float* beu = (const float*)d_in[4];
    const float* Wdu = (const float*)d_in[5];
    const float* bdu = (const float*)d_in[6];
    const float* Wed = (const float*)d_in[7];
    const float* bed = (const float*)d_in[8];
    const float* Wdd = (const float*)d_in[9];
    const float* bdd = (const float*)d_in[10];
    const int* conn = (const int*)d_in[11];
    float* out = (float*)d_out;

    // workspace carve-up (~62.9 MiB), 256-B aligned blocks
    char* w = (char*)d_ws;
    size_t off = 0;
    auto take = [&](size_t bytes) { char* p = w + off; off = (off + bytes + 255) & ~(size_t)255; return p; };
    u16*   X16     = (u16*)take((size_t)NTOK * FF * 2);        // 16 MiB  [WddT alias base]
    u16*   B16     = (u16*)take((size_t)FF * DIM * 2);         // 12 MiB (shared Weu16/Wed16)
    float* WddT    = (float*)X16;                              // 24 MiB alias over X16+B16
    float* WduT    = (float*)take((size_t)FF * DIM * 4);       // 24 MiB
    u16*   A16u    = (u16*)take((size_t)NTOK * DIM * 2);
    u16*   A16d    = (u16*)take((size_t)NTOK * DIM * 2);
    u16*   v_inv16 = (u16*)take((size_t)FF * CC * 2);
    u16*   inv_fd  = (u16*)take((size_t)FF * CC * 2);
    u16*   cclean  = (u16*)take((size_t)FF * CC * 2);
    u16*   cand_u  = (u16*)take((size_t)NTOK * CAP * 2);
    u16*   cand_d  = (u16*)take((size_t)NTOK * CAP * 2);
    int*   cnt_u   = (int*)take(NTOK * 4);
    int*   cnt_d   = (int*)take(NTOK * 4);
    float* vals_up = (float*)take((size_t)NTOK * KK * 4);
    int*   idx_up  = (int*)take((size_t)NTOK * KK * 4);
    float* vals_dn = (float*)take((size_t)NTOK * KK * 4);
    int*   idx_dn  = (int*)take((size_t)NTOK * KK * 4);
    float* sF      = (float*)take(FF * 4);
    float* tuF     = (float*)take(FF * 4);
    float* tdF     = (float*)take(FF * 4);
    double* s64    = (double*)take(FF * 8);
    double* tu64   = (double*)take(FF * 8);
    double* td64   = (double*)take(FF * 8);
    u32*   deg     = (u32*)take(FF * 4);
    u32*   cursor  = (u32*)take(FF * 4);
    u32*   offs    = (u32*)take((FF + 8) * 4);

    dim3 tgrid(FF / 32, DIM / 32), tblk(32, 8);
    dim3 ggrid(FF / 128, NTOK / 128);

    // prep: WduT transpose, bias dots, conn index
    transpose_kernel<<<tgrid, tblk, 0, stream>>>(Wdu, WduT);
    bias_kernel<<<FF, 64, 0, stream>>>(Weu, Wed, bdu, bdd, sF, tuF, tdF, s64, tu64, td64);
    hipMemsetAsync(deg, 0, 2 * FF * sizeof(u32), stream);  // deg + cursor (adjacent)
    dedup_deg_kernel<<<FF, CC, 0, stream>>>(conn, deg);
    scan_kernel<<<1, 256, 0, stream>>>(deg, offs);
    fill_kernel<<<FF, CC, 0, stream>>>(conn, offs, cursor, inv_fd, cclean);

    // bf16 conversions (A both, B = Weu first)
    int nA4 = NTOK * DIM / 4, nB4 = FF * DIM / 4;
    convert_kernel<<<(nA4 + 255) / 256, 256, 0, stream>>>(xu, A16u, nA4);
    convert_kernel<<<(nA4 + 255) / 256, 256, 0, stream>>>(x0, A16d, nA4);
    convert_kernel<<<(nB4 + 255) / 256, 256, 0, stream>>>(Weu, B16, nB4);

    // upstream: approx GEMM -> candidates -> exact rescore
    gemm_mfma<0><<<ggrid, 256, 0, stream>>>(A16u, B16, X16, sF, beu);
    select_kernel<<<NTOK, 256, 0, stream>>>(X16, cand_u, cnt_u);
    fixup_up<<<NTOK, 256, 0, stream>>>(xu, Weu, s64, beu, cand_u, cnt_u, vals_up, idx_up);

    // downstream: B16 <- Wed, approx GEMM, vconn, phase2, candidates, rescore
    convert_kernel<<<(nB4 + 255) / 256, 256, 0, stream>>>(Wed, B16, nB4);
    gemm_mfma<1><<<ggrid, 256, 0, stream>>>(A16d, B16, X16, sF, beu);
    vconn_kernel<<<FF, 256, 0, stream>>>(B16, WduT, offs, inv_fd, v_inv16);
    phase2_kernel<<<NTOK, 256, 0, stream>>>(X16, vals_up, idx_up, offs, inv_fd, v_inv16,
                                            tuF, tdF, bed, ln);
    select_kernel<<<NTOK, 256, 0, stream>>>(X16, cand_d, cnt_d);
    fixup_dn<<<NTOK, 256, 0, stream>>>(x0, Wed, WduT, tu64, td64, bed, ln, cclean,
                                       vals_up, idx_up, cand_d, cnt_d, vals_dn, idx_dn);

    // decodes (decode_up before WddT clobbers X16|B16 region)
    decode_kernel<<<NTOK, 256, 0, stream>>>(vals_up, idx_up, WduT, bdu, out);
    transpose_kernel<<<tgrid, tblk, 0, stream>>>(Wdd, WddT);
    decode_kernel<<<NTOK, 256, 0, stream>>>(vals_dn, idx_dn, WddT, bdd,
                                            out + (size_t)NTOK * DIM);
}

// Round 6
// 855.959 us; speedup vs baseline: 1.6833x; 1.0092x over previous
//
#include <hip/hip_runtime.h>

// SCAESuite R6: chunked L2-resident vconn + fused phase2/select + LDS-radix.
// n=1024 tokens, D=768, F=8192, K=64, C=128. Inputs f32, output f32.
//  - gemm_mfma: bf16 16x16x32 MFMA, 128x128 tile -> X bf16 (selection only)
//  - vconn: 4 launches x 192-elem D-chunk (3MB gather set < 4MB/XCD L2),
//    16-lane sub-entries, bf16 RMW accumulation
//  - phase2sel: per-token scatter + epilogue + radix select, all in LDS
//  - select_up: row staged to LDS f32 once, radix from LDS (KSEL_UP=80)
//  - fixup: exact f64 rescore of candidates (proven R4/R5), bitonic top-64
//  - ws ~61.6 MiB; WddT aliases [X16|B16]; A16 shared between up/down

#define NTOK 1024
#define DIM  768
#define FF   8192
#define KK   64
#define CC   128
#define KSEL_UP 80
#define KSEL_DN 96
#define CAP  128

typedef unsigned short u16;
typedef unsigned int   u32;
typedef __attribute__((ext_vector_type(8))) short short8;
typedef __attribute__((ext_vector_type(4))) float floatx4;

__device__ __forceinline__ float bits2f(u32 v) {
    float f; __builtin_memcpy(&f, &v, 4); return f;
}
__device__ __forceinline__ float bf2f(u16 u) { return bits2f(((u32)u) << 16); }
__device__ __forceinline__ u16 f2bf(float f) {
    u32 u; __builtin_memcpy(&u, &f, 4);
    u32 lsb = (u >> 16) & 1u;
    u += 0x7fffu + lsb;
    return (u16)(u >> 16);
}
__device__ __forceinline__ u32 f2key(float x) {
    u32 u; __builtin_memcpy(&u, &x, 4);
    return (u & 0x80000000u) ? ~u : (u | 0x80000000u);
}

// ---------------- f32 -> bf16 bulk convert (n multiple of 4) -------------------
__global__ __launch_bounds__(256) void convert_kernel(const float* __restrict__ src,
                                                      u16* __restrict__ dst, int n4) {
    int i = blockIdx.x * 256 + threadIdx.x;
    if (i < n4) {
        float4 v = ((const float4*)src)[i];
        ushort4 o;
        o.x = f2bf(v.x); o.y = f2bf(v.y); o.z = f2bf(v.z); o.w = f2bf(v.w);
        ((ushort4*)dst)[i] = o;
    }
}

// ---------------- transpose: f32 [DIM][FF] -> f32 [FF][DIM] ---------------------
__global__ __launch_bounds__(256) void transpose_kernel(const float* __restrict__ in,
                                                        float* __restrict__ out) {
    __shared__ float tile[32][33];
    int f0 = blockIdx.x * 32, d0 = blockIdx.y * 32;
    int tx = threadIdx.x, ty = threadIdx.y;
#pragma unroll
    for (int i = 0; i < 4; ++i)
        tile[ty + 8 * i][tx] = in[(size_t)(d0 + ty + 8 * i) * FF + f0 + tx];
    __syncthreads();
#pragma unroll
    for (int i = 0; i < 4; ++i)
        out[(size_t)(f0 + ty + 8 * i) * DIM + d0 + tx] = tile[tx][ty + 8 * i];
}

// ---------------- bias dots (f32 + f64 copies) ----------------------------------
__global__ __launch_bounds__(64) void bias_kernel(const float* __restrict__ Weu,
                                                  const float* __restrict__ Wed,
                                                  const float* __restrict__ bdu,
                                                  const float* __restrict__ bdd,
                                                  float* __restrict__ sF,
                                                  float* __restrict__ tuF,
                                                  float* __restrict__ tdF,
                                                  double* __restrict__ s64,
                                                  double* __restrict__ tu64,
                                                  double* __restrict__ td64) {
    int f = blockIdx.x, lane = threadIdx.x;
    double su = 0.0, tu = 0.0, td = 0.0;
    for (int i = lane; i < DIM; i += 64) {
        double bu = (double)bdu[i], bd = (double)bdd[i];
        su += (double)Weu[(size_t)f * DIM + i] * bu;
        double w = (double)Wed[(size_t)f * DIM + i];
        tu += w * bu;
        td += w * bd;
    }
#pragma unroll
    for (int off = 32; off; off >>= 1) {
        su += __shfl_xor(su, off);
        tu += __shfl_xor(tu, off);
        td += __shfl_xor(td, off);
    }
    if (lane == 0) {
        sF[f] = (float)su; tuF[f] = (float)tu; tdF[f] = (float)td;
        s64[f] = su; tu64[f] = tu; td64[f] = td;
    }
}

// ---------------- bf16 MFMA GEMM: X[t,f] = sum_d A[t,d]*B[f,d] ------------------
template <int MODE>
__global__ __launch_bounds__(256) void gemm_mfma(const u16* __restrict__ A16,
                                                 const u16* __restrict__ B16,
                                                 u16* __restrict__ Xout,
                                                 const float* __restrict__ sF,
                                                 const float* __restrict__ b_enc) {
    __shared__ __align__(16) u16 As[128 * 40];
    __shared__ __align__(16) u16 Bs[128 * 40];
    int tid = threadIdx.x;
    int wave = tid >> 6, lane = tid & 63;
    int lm = lane & 15, quad = lane >> 4;
    int m0 = blockIdx.y * 128, n0 = blockIdx.x * 128;
    int wm = (wave >> 1) * 64, wn = (wave & 1) * 64;
    floatx4 acc[4][4];
#pragma unroll
    for (int i = 0; i < 4; ++i)
#pragma unroll
        for (int j = 0; j < 4; ++j)
            acc[i][j] = (floatx4){0.f, 0.f, 0.f, 0.f};
    int r = tid >> 2;
    int s = (tid & 3) * 8;
    const u16* gA = A16 + (size_t)(m0 + r) * DIM + s;
    const u16* gB = B16 + (size_t)(n0 + r) * DIM + s;
    for (int k0 = 0; k0 < DIM; k0 += 32) {
        __syncthreads();
        *(int4*)&As[r * 40 + s]          = *(const int4*)(gA + k0);
        *(int4*)&As[(r + 64) * 40 + s]   = *(const int4*)(gA + (size_t)64 * DIM + k0);
        *(int4*)&Bs[r * 40 + s]          = *(const int4*)(gB + k0);
        *(int4*)&Bs[(r + 64) * 40 + s]   = *(const int4*)(gB + (size_t)64 * DIM + k0);
        __syncthreads();
        short8 af[4], bfr[4];
#pragma unroll
        for (int mi = 0; mi < 4; ++mi)
            af[mi] = *(const short8*)&As[(wm + mi * 16 + lm) * 40 + quad * 8];
#pragma unroll
        for (int ni = 0; ni < 4; ++ni)
            bfr[ni] = *(const short8*)&Bs[(wn + ni * 16 + lm) * 40 + quad * 8];
#pragma unroll
        for (int mi = 0; mi < 4; ++mi)
#pragma unroll
            for (int ni = 0; ni < 4; ++ni)
                acc[mi][ni] = __builtin_amdgcn_mfma_f32_16x16x32_bf16(
                    af[mi], bfr[ni], acc[mi][ni], 0, 0, 0);
    }
#pragma unroll
    for (int ni = 0; ni < 4; ++ni) {
        int col = n0 + wn + ni * 16 + lm;
        float sub = 0.f, bb = 0.f;
        if (MODE == 0) { sub = sF[col]; bb = b_enc[col]; }
#pragma unroll
        for (int mi = 0; mi < 4; ++mi) {
#pragma unroll
            for (int reg = 0; reg < 4; ++reg) {
                int row = m0 + wm + mi * 16 + quad * 4 + reg;
                float v = acc[mi][ni][reg];
                if (MODE == 0) { v = v - sub + bb; v = v > 0.f ? v : 0.f; }
                Xout[(size_t)row * FF + col] = f2bf(v);
            }
        }
    }
}

// ---------------- select_up: LDS-staged row + radix top-KSEL_UP -----------------
__global__ __launch_bounds__(256) void select_up_kernel(const u16* __restrict__ X16,
                                                        u16* __restrict__ cand,
                                                        int* __restrict__ cnt) {
    __shared__ float xr[FF];
    __shared__ u32 hist[256];
    __shared__ u32 sh_prefix;
    __shared__ int sh_k;
    __shared__ u32 sh_cntG, sh_cntE;
    __shared__ int eqidx[256];
    const int rrow = blockIdx.x, tid = threadIdx.x;
    const ushort4* src = (const ushort4*)(X16 + (size_t)rrow * FF);
    for (int i = tid; i < FF / 4; i += 256) {
        ushort4 u = src[i];
        xr[i * 4]     = bf2f(u.x);
        xr[i * 4 + 1] = bf2f(u.y);
        xr[i * 4 + 2] = bf2f(u.z);
        xr[i * 4 + 3] = bf2f(u.w);
    }
    if (tid == 0) { sh_prefix = 0; sh_k = KSEL_UP; }
    __syncthreads();
    for (int pass = 0; pass < 4; ++pass) {
        hist[tid] = 0;
        __syncthreads();
        u32 prefix = sh_prefix;
        int shift = 24 - 8 * pass;
        for (int i = tid; i < FF; i += 256) {
            u32 key = f2key(xr[i]);
            if (pass == 0 || (key >> (shift + 8)) == prefix)
                atomicAdd(&hist[(key >> shift) & 255u], 1u);
        }
        __syncthreads();
        if (tid == 0) {
            int rem = sh_k;
            int b = 255;
            for (; b > 0; --b) {
                int h = (int)hist[b];
                if (rem <= h) break;
                rem -= h;
            }
            sh_prefix = (prefix << 8) | (u32)b;
            sh_k = rem;
        }
        __syncthreads();
    }
    u32 T = sh_prefix;
    if (tid == 0) { sh_cntG = 0; sh_cntE = 0; }
    __syncthreads();
    u16* cr = cand + (size_t)rrow * CAP;
    for (int i = tid; i < FF; i += 256) {
        u32 key = f2key(xr[i]);
        if (key > T) {
            u32 p = atomicAdd(&sh_cntG, 1u);
            if (p < CAP) cr[p] = (u16)i;
        } else if (key == T) {
            u32 p = atomicAdd(&sh_cntE, 1u);
            if (p < 256) eqidx[p] = i;
        }
    }
    __syncthreads();
    if (tid == 0) {
        int G = (int)sh_cntG; if (G > CAP) G = CAP;
        int ne = (int)sh_cntE; if (ne > 256) ne = 256;
        int total = G;
        for (int q = 0; q < ne && total < CAP; ++q) cr[total++] = (u16)eqidx[q];
        cnt[rrow] = total;
    }
}

// ---------------- bitonic sort of 128 (desc by val, asc idx) --------------------
__device__ __forceinline__ bool sort_before(double av, int ai, double bv, int bi) {
    return (av > bv) || (av == bv && ai < bi);
}
__device__ void bitonic128(double* sv, int* si, int tid) {
    for (int k = 2; k <= 128; k <<= 1) {
        for (int j = k >> 1; j > 0; j >>= 1) {
            __syncthreads();
            if (tid < 64) {
                int i = ((tid & ~(j - 1)) << 1) | (tid & (j - 1));
                int l = i, rr = i + j;
                bool bfirst = sort_before(sv[rr], si[rr], sv[l], si[l]);
                bool doswap = ((i & k) == 0) ? bfirst : !bfirst;
                if (doswap) {
                    double tv = sv[l]; sv[l] = sv[rr]; sv[rr] = tv;
                    int ti = si[l]; si[l] = si[rr]; si[rr] = ti;
                }
            }
        }
    }
    __syncthreads();
}

// ---------------- exact rescore (up) --------------------------------------------
__global__ __launch_bounds__(256) void fixup_up(const float* __restrict__ xu,
                                                const float* __restrict__ Weu,
                                                const double* __restrict__ s64,
                                                const float* __restrict__ beu,
                                                const u16* __restrict__ cand,
                                                const int* __restrict__ cnt,
                                                float* __restrict__ vals,
                                                int* __restrict__ idxs) {
    __shared__ float xrow[DIM];
    __shared__ double sv[128];
    __shared__ int si[128];
    int t = blockIdx.x, tid = threadIdx.x, wave = tid >> 6, lane = tid & 63;
    for (int i = tid; i < DIM; i += 256) xrow[i] = xu[(size_t)t * DIM + i];
    for (int c = tid; c < 128; c += 256) { sv[c] = -1.0e300; si[c] = 0x7fffffff; }
    __syncthreads();
    int nc = cnt[t]; if (nc > 128) nc = 128;
    for (int c = wave; c < nc; c += 4) {
        int f = (int)cand[(size_t)t * CAP + c];
        const float* wr = Weu + (size_t)f * DIM;
        double p = 0.0;
#pragma unroll
        for (int i = 0; i < 12; ++i) {
            int d = lane + 64 * i;
            p += (double)xrow[d] * (double)wr[d];
        }
#pragma unroll
        for (int off = 32; off; off >>= 1) p += __shfl_xor(p, off);
        if (lane == 0) {
            double v = p - s64[f] + (double)beu[f];
            v = v > 0.0 ? v : 0.0;
            sv[c] = v; si[c] = f;
        }
    }
    __syncthreads();
    bitonic128(sv, si, tid);
    if (tid < KK) {
        vals[(size_t)t * KK + tid] = (float)sv[tid];
        idxs[(size_t)t * KK + tid] = si[tid];
    }
}

// ---------------- exact rescore (down) ------------------------------------------
__global__ __launch_bounds__(256) void fixup_dn(const float* __restrict__ x0,
                                                const float* __restrict__ Wed,
                                                const float* __restrict__ WduT,
                                                const double* __restrict__ tu64,
                                                const double* __restrict__ td64,
                                                const float* __restrict__ bed,
                                                const float* __restrict__ ln,
                                                const u16* __restrict__ cclean,
                                                const float* __restrict__ vals_up,
                                                const int* __restrict__ idx_up,
                                                const u16* __restrict__ cand,
                                                const int* __restrict__ cnt,
                                                float* __restrict__ vals,
                                                int* __restrict__ idxs) {
    __shared__ float xrow[DIM];
    __shared__ u32 bm[256];
    __shared__ int fl[KK];
    __shared__ float zl[KK];
    __shared__ double sv[128];
    __shared__ int si[128];
    int t = blockIdx.x, tid = threadIdx.x, wave = tid >> 6, lane = tid & 63;
    for (int i = tid; i < DIM; i += 256) xrow[i] = x0[(size_t)t * DIM + i];
    if (tid < 256) bm[tid] = 0;
    for (int c = tid; c < 128; c += 256) { sv[c] = -1.0e300; si[c] = 0x7fffffff; }
    __syncthreads();
    if (tid < KK) {
        int f = idx_up[(size_t)t * KK + tid];
        fl[tid] = f; zl[tid] = vals_up[(size_t)t * KK + tid];
        atomicOr(&bm[f >> 5], 1u << (f & 31));
    }
    __syncthreads();
    int nc = cnt[t]; if (nc > 128) nc = 128;
    double lnt = (double)ln[t];
    for (int c = wave; c < nc; c += 4) {
        int f = (int)cand[(size_t)t * CAP + c];
        const float* wr = Wed + (size_t)f * DIM;
        double p = 0.0;
#pragma unroll
        for (int i = 0; i < 12; ++i) {
            int d = lane + 64 * i;
            p += (double)xrow[d] * (double)wr[d];
        }
        const u16* crow = cclean + (size_t)f * CC;
        int e0 = (int)crow[lane], e1 = (int)crow[lane + 64];
        bool h0 = (e0 != 0xFFFF) && ((bm[e0 >> 5] >> (e0 & 31)) & 1u);
        bool h1 = (e1 != 0xFFFF) && ((bm[e1 >> 5] >> (e1 & 31)) & 1u);
        unsigned long long m0 = __ballot(h0), m1 = __ballot(h1);
        while (m0 | m1) {
            int fu;
            if (m0) {
                int b = __ffsll((long long)m0) - 1; m0 &= m0 - 1;
                fu = __shfl(e0, b);
            } else {
                int b = __ffsll((long long)m1) - 1; m1 &= m1 - 1;
                fu = __shfl(e1, b);
            }
            unsigned long long zm = __ballot(fl[lane & 63] == fu && lane < KK);
            float z = zl[__ffsll((long long)zm) - 1];
            const float* du = WduT + (size_t)fu * DIM;
            double vp = 0.0;
#pragma unroll
            for (int i = 0; i < 12; ++i) {
                int d = lane + 64 * i;
                vp += (double)wr[d] * (double)du[d];
            }
            p += (double)z * vp;
        }
#pragma unroll
        for (int off = 32; off; off >>= 1) p += __shfl_xor(p, off);
        if (lane == 0) {
            double v = (p + tu64[f]) / lnt + (double)bed[f] - td64[f];
            sv[c] = v; si[c] = f;
        }
    }
    __syncthreads();
    bitonic128(sv, si, tid);
    if (tid < KK) {
        vals[(size_t)t * KK + tid] = (float)sv[tid];
        idxs[(size_t)t * KK + tid] = si[tid];
    }
}

// ---------------- conn dedupe + inverse-index build -----------------------------
__global__ __launch_bounds__(128) void dedup_deg_kernel(const int* __restrict__ conn,
                                                        u32* __restrict__ deg) {
    __shared__ int row[CC];
    int fd = blockIdx.x, c = threadIdx.x;
    int v = conn[(size_t)fd * CC + c];
    row[c] = v;
    __syncthreads();
    bool dup = false;
    for (int j = 0; j < c; ++j) dup |= (row[j] == v);
    if (!dup) atomicAdd(&deg[v], 1u);
}

__global__ __launch_bounds__(256) void scan_kernel(const u32* __restrict__ deg,
                                                   u32* __restrict__ offs) {
    __shared__ u32 sdeg[FF];
    __shared__ u32 part[256];
    int tid = threadIdx.x;
    for (int i = tid; i < FF; i += 256) sdeg[i] = deg[i];
    __syncthreads();
    u32 s = 0;
    for (int j = 0; j < 32; ++j) s += sdeg[tid * 32 + j];
    part[tid] = s;
    __syncthreads();
    if (tid == 0) {
        u32 run = 0;
        for (int i = 0; i < 256; ++i) { u32 v = part[i]; part[i] = run; run += v; }
        offs[FF] = run;
    }
    __syncthreads();
    u32 run = part[tid];
    for (int j = 0; j < 32; ++j) { offs[tid * 32 + j] = run; run += sdeg[tid * 32 + j]; }
}

__global__ __launch_bounds__(128) void fill_kernel(const int* __restrict__ conn,
                                                   const u32* __restrict__ offs,
                                                   u32* __restrict__ cursor,
                                                   u16* __restrict__ inv_fd,
                                                   u16* __restrict__ cclean) {
    __shared__ int row[CC];
    int fd = blockIdx.x, c = threadIdx.x;
    int v = conn[(size_t)fd * CC + c];
    row[c] = v;
    __syncthreads();
    bool dup = false;
    for (int j = 0; j < c; ++j) dup |= (row[j] == v);
    cclean[(size_t)fd * CC + c] = dup ? (u16)0xFFFF : (u16)v;
    if (!dup) {
        u32 slot = atomicAdd(&cursor[v], 1u);
        inv_fd[offs[v] + slot] = (u16)fd;
    }
}

// ---------------- vconn: one 192-elem D-chunk, 16-lane sub-entries --------------
// Gather working set per launch = 8192*192*2B = 3 MB < 4 MB/XCD L2.
__global__ __launch_bounds__(256) void vconn_chunk(const u16* __restrict__ Wed16,
                                                   const float* __restrict__ WduT,
                                                   const u32* __restrict__ offs,
                                                   const u16* __restrict__ inv_fd,
                                                   u16* __restrict__ v_inv16,
                                                   int chunk, int first) {
    __shared__ float row[192];
    int fu = blockIdx.x, tid = threadIdx.x;
    if (tid < 192) row[tid] = WduT[(size_t)fu * DIM + chunk * 192 + tid];
    __syncthreads();
    u32 s = offs[fu], e = offs[fu + 1];
    int wave = tid >> 6, lane = tid & 63;
    int sub = lane >> 4, sl = lane & 15;
    for (u32 p0 = s + (u32)wave * 4; p0 < e; p0 += 16) {
        u32 p = p0 + (u32)sub;
        bool valid = p < e;
        float a = 0.f;
        if (valid) {
            int fd = (int)inv_fd[p];
            const u16* wr = Wed16 + (size_t)fd * DIM + chunk * 192;
#pragma unroll
            for (int i = 0; i < 12; ++i)
                a = fmaf(bf2f(wr[sl + 16 * i]), row[sl + 16 * i], a);
        }
        a += __shfl_xor(a, 1);
        a += __shfl_xor(a, 2);
        a += __shfl_xor(a, 4);
        a += __shfl_xor(a, 8);
        if (valid && sl == 0) {
            if (first) v_inv16[p] = f2bf(a);
            else       v_inv16[p] = f2bf(bf2f(v_inv16[p]) + a);
        }
    }
}

// ---------------- phase2 + select_dn fused (all in LDS) -------------------------
__global__ __launch_bounds__(256) void phase2sel(const u16* __restrict__ X16,
                                                 const float* __restrict__ vals_up,
                                                 const int* __restrict__ idx_up,
                                                 const u32* __restrict__ offs,
                                                 const u16* __restrict__ inv_fd,
                                                 const u16* __restrict__ v_inv16,
                                                 const float* __restrict__ tuF,
                                                 const float* __restrict__ tdF,
                                                 const float* __restrict__ bed,
                                                 const float* __restrict__ ln,
                                                 u16* __restrict__ cand,
                                                 int* __restrict__ cnt) {
    __shared__ float acc[FF];
    __shared__ float z[KK];
    __shared__ int fidx[KK];
    __shared__ u32 hist[256];
    __shared__ u32 sh_prefix;
    __shared__ int sh_k;
    __shared__ u32 sh_cntG, sh_cntE;
    __shared__ int eqidx[256];
    int t = blockIdx.x, tid = threadIdx.x;
    for (int i = tid; i < FF; i += 256) acc[i] = 0.f;
    if (tid < KK) { z[tid] = vals_up[(size_t)t * KK + tid]; fidx[tid] = idx_up[(size_t)t * KK + tid]; }
    if (tid == 0) { sh_prefix = 0; sh_k = KSEL_DN; }
    __syncthreads();
    for (int j = 0; j < KK; ++j) {
        float zj = z[j];
        int f = fidx[j];
        u32 s = offs[f], e = offs[f + 1];
        for (u32 p = s + tid; p < e; p += 256)
            atomicAdd(&acc[(int)inv_fd[p]], zj * bf2f(v_inv16[p]));
    }
    __syncthreads();
    float lnv = ln[t];
    const ushort4* xsrc = (const ushort4*)(X16 + (size_t)t * FF);
    for (int i = tid; i < FF / 4; i += 256) {
        ushort4 u = xsrc[i];
#pragma unroll
        for (int q = 0; q < 4; ++q) {
            int idx = i * 4 + q;
            float xv = bf2f(q == 0 ? u.x : q == 1 ? u.y : q == 2 ? u.z : u.w);
            float v = xv + acc[idx] + tuF[idx];
            acc[idx] = v / lnv + bed[idx] - tdF[idx];
        }
    }
    __syncthreads();
    // radix select over LDS acc
    for (int pass = 0; pass < 4; ++pass) {
        hist[tid] = 0;
        __syncthreads();
        u32 prefix = sh_prefix;
        int shift = 24 - 8 * pass;
        for (int i = tid; i < FF; i += 256) {
            u32 key = f2key(acc[i]);
            if (pass == 0 || (key >> (shift + 8)) == prefix)
                atomicAdd(&hist[(key >> shift) & 255u], 1u);
        }
        __syncthreads();
        if (tid == 0) {
            int rem = sh_k;
            int b = 255;
            for (; b > 0; --b) {
                int h = (int)hist[b];
                if (rem <= h) break;
                rem -= h;
            }
            sh_prefix = (prefix << 8) | (u32)b;
            sh_k = rem;
        }
        __syncthreads();
    }
    u32 T = sh_prefix;
    if (tid == 0) { sh_cntG = 0; sh_cntE = 0; }
    __syncthreads();
    u16* cr = cand + (size_t)t * CAP;
    for (int i = tid; i < FF; i += 256) {
        u32 key = f2key(acc[i]);
        if (key > T) {
            u32 p = atomicAdd(&sh_cntG, 1u);
            if (p < CAP) cr[p] = (u16)i;
        } else if (key == T) {
            u32 p = atomicAdd(&sh_cntE, 1u);
            if (p < 256) eqidx[p] = i;
        }
    }
    __syncthreads();
    if (tid == 0) {
        int G = (int)sh_cntG; if (G > CAP) G = CAP;
        int ne = (int)sh_cntE; if (ne > 256) ne = 256;
        int total = G;
        for (int q = 0; q < ne && total < CAP; ++q) cr[total++] = (u16)eqidx[q];
        cnt[t] = total;
    }
}

// ---------------- sparse decode -------------------------------------------------
__global__ __launch_bounds__(256) void decode_kernel(const float* __restrict__ vals,
                                                     const int* __restrict__ idxs,
                                                     const float* __restrict__ WdT,
                                                     const float* __restrict__ b_dec,
                                                     float* __restrict__ outp) {
    __shared__ float z[KK];
    __shared__ int fidx[KK];
    int t = blockIdx.x, tid = threadIdx.x;
    if (tid < KK) { z[tid] = vals[(size_t)t * KK + tid]; fidx[tid] = idxs[(size_t)t * KK + tid]; }
    __syncthreads();
    float a0 = 0.f, a1 = 0.f, a2 = 0.f;
    for (int j = 0; j < KK; ++j) {
        const float* wr = WdT + (size_t)fidx[j] * DIM;
        float zj = z[j];
        a0 = fmaf(zj, wr[tid], a0);
        a1 = fmaf(zj, wr[tid + 256], a1);
        a2 = fmaf(zj, wr[tid + 512], a2);
    }
    outp[(size_t)t * DIM + tid]       = a0 + b_dec[tid];
    outp[(size_t)t * DIM + tid + 256] = a1 + b_dec[tid + 256];
    outp[(size_t)t * DIM + tid + 512] = a2 + b_dec[tid + 512];
}

extern "C" void kernel_launch(void* const* d_in, const int* in_sizes, int n_in,
                              void* d_out, int out_size, void* d_ws, size_t ws_size,
                              hipStream_t stream) {
    const float* x0  = (const float*)d_in[0];
    const float* xu  = (const float*)d_in[1];
    const float* ln  = (const float*)d_in[2];
    const float* Weu = (const float*)d_in[3];
    const float* beu = (const float*)d_in[4];
    const float* Wdu = (const float*)d_in[5];
    const float* bdu = (const float*)d_in[6];
    const float* Wed = (const float*)d_in[7];
    const float* bed = (const float*)d_in[8];
    const float* Wdd = (const float*)d_in[9];
    const float* bdd = (const float*)d_in[10];
    const int* conn = (const int*)d_in[11];
    float* out = (float*)d_out;

    // workspace carve-up (~61.6 MiB)
    char* w = (char*)d_ws;
    size_t off = 0;
    auto take = [&](size_t bytes) { char* p = w + off; off = (off + bytes + 255) & ~(size_t)255; return p; };
    u16*   X16     = (u16*)take((size_t)NTOK * FF * 2);        // 16 MiB
    u16*   B16     = (u16*)take((size_t)FF * DIM * 2);         // 12 MiB (Weu16 then Wed16)
    float* WddT    = (float*)X16;                              // 24 MiB alias over X16+B16
    float* WduT    = (float*)take((size_t)FF * DIM * 4);       // 24 MiB
    u16*   A16     = (u16*)take((size_t)NTOK * DIM * 2);       // 1.5 MiB (shared up/down)
    u16*   v_inv16 = (u16*)take((size_t)FF * CC * 2);
    u16*   inv_fd  = (u16*)take((size_t)FF * CC * 2);
    u16*   cclean  = (u16*)take((size_t)FF * CC * 2);
    u16*   cand_u  = (u16*)take((size_t)NTOK * CAP * 2);
    u16*   cand_d  = (u16*)take((size_t)NTOK * CAP * 2);
    int*   cnt_u   = (int*)take(NTOK * 4);
    int*   cnt_d   = (int*)take(NTOK * 4);
    float* vals_up = (float*)take((size_t)NTOK * KK * 4);
    int*   idx_up  = (int*)take((size_t)NTOK * KK * 4);
    float* vals_dn = (float*)take((size_t)NTOK * KK * 4);
    int*   idx_dn  = (int*)take((size_t)NTOK * KK * 4);
    float* sF      = (float*)take(FF * 4);
    float* tuF     = (float*)take(FF * 4);
    float* tdF     = (float*)take(FF * 4);
    double* s64    = (double*)take(FF * 8);
    double* tu64   = (double*)take(FF * 8);
    double* td64   = (double*)take(FF * 8);
    u32*   deg     = (u32*)take(FF * 4);
    u32*   cursor  = (u32*)take(FF * 4);
    u32*   offs    = (u32*)take((FF + 8) * 4);

    dim3 tgrid(FF / 32, DIM / 32), tblk(32, 8);
    dim3 ggrid(FF / 128, NTOK / 128);
    int nA4 = NTOK * DIM / 4, nB4 = FF * DIM / 4;

    // prep
    transpose_kernel<<<tgrid, tblk, 0, stream>>>(Wdu, WduT);
    bias_kernel<<<FF, 64, 0, stream>>>(Weu, Wed, bdu, bdd, sF, tuF, tdF, s64, tu64, td64);
    hipMemsetAsync(deg, 0, 2 * FF * sizeof(u32), stream);  // deg + cursor (adjacent)
    dedup_deg_kernel<<<FF, CC, 0, stream>>>(conn, deg);
    scan_kernel<<<1, 256, 0, stream>>>(deg, offs);
    fill_kernel<<<FF, CC, 0, stream>>>(conn, offs, cursor, inv_fd, cclean);

    // upstream
    convert_kernel<<<(nA4 + 255) / 256, 256, 0, stream>>>(xu, A16, nA4);
    convert_kernel<<<(nB4 + 255) / 256, 256, 0, stream>>>(Weu, B16, nB4);
    gemm_mfma<0><<<ggrid, 256, 0, stream>>>(A16, B16, X16, sF, beu);
    select_up_kernel<<<NTOK, 256, 0, stream>>>(X16, cand_u, cnt_u);
    fixup_up<<<NTOK, 256, 0, stream>>>(xu, Weu, s64, beu, cand_u, cnt_u, vals_up, idx_up);

    // downstream
    convert_kernel<<<(nA4 + 255) / 256, 256, 0, stream>>>(x0, A16, nA4);
    convert_kernel<<<(nB4 + 255) / 256, 256, 0, stream>>>(Wed, B16, nB4);
    gemm_mfma<1><<<ggrid, 256, 0, stream>>>(A16, B16, X16, sF, beu);
    vconn_chunk<<<FF, 256, 0, stream>>>(B16, WduT, offs, inv_fd, v_inv16, 0, 1);
    vconn_chunk<<<FF, 256, 0, stream>>>(B16, WduT, offs, inv_fd, v_inv16, 1, 0);
    vconn_chunk<<<FF, 256, 0, stream>>>(B16, WduT, offs, inv_fd, v_inv16, 2, 0);
    vconn_chunk<<<FF, 256, 0, stream>>>(B16, WduT, offs, inv_fd, v_inv16, 3, 0);
    phase2sel<<<NTOK, 256, 0, stream>>>(X16, vals_up, idx_up, offs, inv_fd, v_inv16,
                                        tuF, tdF, bed, ln, cand_d, cnt_d);
    fixup_dn<<<NTOK, 256, 0, stream>>>(x0, Wed, WduT, tu64, td64, bed, ln, cclean,
                                       vals_up, idx_up, cand_d, cnt_d, vals_dn, idx_dn);

    // decodes (decode_up before WddT clobbers X16|B16 region)
    decode_kernel<<<NTOK, 256, 0, stream>>>(vals_up, idx_up, WduT, bdu, out);
    transpose_kernel<<<tgrid, tblk, 0, stream>>>(Wdd, WddT);
    decode_kernel<<<NTOK, 256, 0, stream>>>(vals_dn, idx_dn, WddT, bdd,
                                            out + (size_t)NTOK * DIM);
}